// Round 5
// baseline (4428.982 us; speedup 1.0000x reference)
//
#include <hip/hip_runtime.h>
#include <hip/hip_bf16.h>

// B=16, N=256, P=8, D=512, H=8, E=4096, dh=512, scale=1/8.
// HYPOTHESIS (round 5): d_out is FP32 (reference outputs are float32; the
// "bf16" in the harness label refers to bf16-rounding of the np reference /
// tolerance floor, not the buffer dtype). Rounds 1-4's bit-identical error
// 12.84 matches max|ref - bf16pair_as_fp32| ~= 13.2 quantitatively.
// Pipeline (precision-tiered):
//   split x,W into bf16 hi+lo; embed/Q/K via 3-product split-bf16 MFMA GEMM
//   (near-fp32 accuracy) -> q,k fp32; scores+softmax in fp32 scalar ->
//   attn_weights fp32 to d_out; V + output GEMMs in plain bf16 MFMA
//   (out0 threshold is 2% of 9.56); final out0 fp32 to d_out.
// ws peak 256 MiB (round1 proved ws_size >= 288 MiB).

typedef unsigned short u16;
typedef __attribute__((ext_vector_type(8))) short vbf16x8;   // 8 bf16 = 4 VGPR
typedef __attribute__((ext_vector_type(4))) float vf32x4;    // MFMA acc

#define MFMA_BF16(a, b, c) __builtin_amdgcn_mfma_f32_16x16x32_bf16(a, b, c, 0, 0, 0)

__device__ __forceinline__ u16 f2bf(float f) {
    unsigned u = __float_as_uint(f);
    u += 0x7fffu + ((u >> 16) & 1u);   // RNE
    return (u16)(u >> 16);
}
__device__ __forceinline__ float bf2f(u16 u) {
    return __uint_as_float(((unsigned)u) << 16);
}

__device__ __forceinline__ void gld16(const u16* g, u16* l) {
    // async global->LDS, 16B/lane; LDS dest = wave-uniform base + lane*16
    __builtin_amdgcn_global_load_lds((const __attribute__((address_space(1))) void*)g,
                                     (__attribute__((address_space(3))) void*)l,
                                     16, 0, 0);
}

// ---------------- fp32 -> bf16 hi/lo split ----------------------------------
__global__ __launch_bounds__(256) void split2(const float* __restrict__ s,
                                              u16* __restrict__ dh,
                                              u16* __restrict__ dl) {
    const size_t i = ((size_t)blockIdx.x * 256 + threadIdx.x) * 4;
    const float4 v = *(const float4*)(s + i);
    float vv[4] = {v.x, v.y, v.z, v.w};
#pragma unroll
    for (int j = 0; j < 4; ++j) {
        const u16 h = f2bf(vv[j]);
        dh[i + j] = h;
        dl[i + j] = f2bf(vv[j] - bf2f(h));
    }
}

// ---------------- fp32 -> bf16 (hi only) ------------------------------------
__global__ __launch_bounds__(256) void tob16(const float* __restrict__ s,
                                             u16* __restrict__ d) {
    const size_t i = ((size_t)blockIdx.x * 256 + threadIdx.x) * 4;
    const float4 v = *(const float4*)(s + i);
    d[i + 0] = f2bf(v.x); d[i + 1] = f2bf(v.y);
    d[i + 2] = f2bf(v.z); d[i + 3] = f2bf(v.w);
}

// ---------------- split-bf16 NT GEMM: C = (Ah+Al) @ (Bh+Bl)^T + bias --------
// 3-product MFMA (drops lo*lo, ~2^-18 per-term error). 128x128 tile, BK=64.
// OUTMODE 0: +pos_embed, write hi/lo bf16 pair. OUTMODE 1: write fp32.
template <int OUTMODE>
__global__ __launch_bounds__(256)
void gemm3_nt(const u16* __restrict__ Ah, const u16* __restrict__ Al,
              const u16* __restrict__ Bh, const u16* __restrict__ Bl,
              const float* __restrict__ bias, const float* __restrict__ pos,
              u16* __restrict__ Chi, u16* __restrict__ Clo,
              float* __restrict__ Cf) {
    __shared__ __align__(16) u16 Ahs[128 * 64];
    __shared__ __align__(16) u16 Als[128 * 64];
    __shared__ __align__(16) u16 Bhs[128 * 64];
    __shared__ __align__(16) u16 Bls[128 * 64];
    const int t = threadIdx.x;
    const int lane = t & 63, w = t >> 6;
    const int wr = (w >> 1) << 6, wc = (w & 1) << 6;
    const int l15 = lane & 15, lg = lane >> 4;
    const int m0 = (blockIdx.x >> 5) << 7, n0 = (blockIdx.x & 31) << 7;

    vf32x4 acc[4][4] = {};

    for (int k0 = 0; k0 < 4096; k0 += 64) {
#pragma unroll
        for (int i = 0; i < 4; ++i) {
            const int c = t + (i << 8);           // chunk 0..1023 (16B each)
            const int row = c >> 3, c8 = (c & 7) << 3;
            const size_t goA = (((size_t)(m0 + row)) << 12) + k0 + c8;
            const size_t goB = (((size_t)(n0 + row)) << 12) + k0 + c8;
            gld16(Ah + goA, Ahs + c * 8);
            gld16(Al + goA, Als + c * 8);
            gld16(Bh + goB, Bhs + c * 8);
            gld16(Bl + goB, Bls + c * 8);
        }
        __syncthreads();
#pragma unroll
        for (int kk = 0; kk < 2; ++kk) {
            vbf16x8 ah[4], al[4], bh[4], bl[4];
#pragma unroll
            for (int m = 0; m < 4; ++m) {
                const int off = (wr + m * 16 + l15) * 64 + kk * 32 + lg * 8;
                ah[m] = *(const vbf16x8*)(Ahs + off);
                al[m] = *(const vbf16x8*)(Als + off);
            }
#pragma unroll
            for (int n = 0; n < 4; ++n) {
                const int off = (wc + n * 16 + l15) * 64 + kk * 32 + lg * 8;
                bh[n] = *(const vbf16x8*)(Bhs + off);
                bl[n] = *(const vbf16x8*)(Bls + off);
            }
#pragma unroll
            for (int m = 0; m < 4; ++m)
#pragma unroll
                for (int n = 0; n < 4; ++n) {
                    acc[m][n] = MFMA_BF16(al[m], bh[n], acc[m][n]);
                    acc[m][n] = MFMA_BF16(ah[m], bl[n], acc[m][n]);
                    acc[m][n] = MFMA_BF16(ah[m], bh[n], acc[m][n]);
                }
        }
        __syncthreads();
    }

#pragma unroll
    for (int m = 0; m < 4; ++m)
#pragma unroll
        for (int n = 0; n < 4; ++n) {
            const int col = n0 + wc + n * 16 + l15;
            const float bv = bias[col];
#pragma unroll
            for (int r = 0; r < 4; ++r) {
                const int row = m0 + wr + m * 16 + lg * 4 + r;
                float v = acc[m][n][r] + bv;
                if (OUTMODE == 0) {
                    v += pos[((size_t)(row & 255) << 12) + col];
                    const u16 h = f2bf(v);
                    Chi[((size_t)row << 12) + col] = h;
                    Clo[((size_t)row << 12) + col] = f2bf(v - bf2f(h));
                } else {
                    Cf[((size_t)row << 12) + col] = v;
                }
            }
        }
}

// ---------------- plain bf16 NT GEMM (V and output projections) -------------
template <typename OutT>
__global__ __launch_bounds__(256)
void gemm_nt(const u16* __restrict__ A, const u16* __restrict__ Bw,
             const float* __restrict__ bias, OutT* __restrict__ C) {
    __shared__ __align__(16) u16 As[128 * 64];
    __shared__ __align__(16) u16 Bs[128 * 64];
    const int t = threadIdx.x;
    const int lane = t & 63, w = t >> 6;
    const int wr = (w >> 1) << 6, wc = (w & 1) << 6;
    const int l15 = lane & 15, lg = lane >> 4;
    const int m0 = (blockIdx.x >> 5) << 7, n0 = (blockIdx.x & 31) << 7;

    vf32x4 acc[4][4] = {};

    for (int k0 = 0; k0 < 4096; k0 += 64) {
#pragma unroll
        for (int i = 0; i < 4; ++i) {
            const int c = t + (i << 8);
            const int row = c >> 3, c8 = (c & 7) << 3;
            gld16(A  + (((size_t)(m0 + row)) << 12) + k0 + c8, As + c * 8);
            gld16(Bw + (((size_t)(n0 + row)) << 12) + k0 + c8, Bs + c * 8);
        }
        __syncthreads();
#pragma unroll
        for (int kk = 0; kk < 2; ++kk) {
            vbf16x8 af[4], bfr[4];
#pragma unroll
            for (int m = 0; m < 4; ++m)
                af[m] = *(const vbf16x8*)(As + (wr + m * 16 + l15) * 64 + kk * 32 + lg * 8);
#pragma unroll
            for (int n = 0; n < 4; ++n)
                bfr[n] = *(const vbf16x8*)(Bs + (wc + n * 16 + l15) * 64 + kk * 32 + lg * 8);
#pragma unroll
            for (int m = 0; m < 4; ++m)
#pragma unroll
                for (int n = 0; n < 4; ++n)
                    acc[m][n] = MFMA_BF16(af[m], bfr[n], acc[m][n]);
        }
        __syncthreads();
    }

#pragma unroll
    for (int m = 0; m < 4; ++m)
#pragma unroll
        for (int n = 0; n < 4; ++n) {
            const int col = n0 + wc + n * 16 + l15;
            const float bv = bias[col];
#pragma unroll
            for (int r = 0; r < 4; ++r) {
                const int row = m0 + wr + m * 16 + lg * 4 + r;
                const float v = acc[m][n][r] + bv;
                if constexpr (sizeof(OutT) == 2)
                    C[((size_t)row << 12) + col] = f2bf(v);
                else
                    C[((size_t)row << 12) + col] = v;
            }
        }
}

// ---------------- fp32 scores + softmax -> attn_weights (output 1, fp32) ----
// block rid = (b*8+h)*256 + n; thread m computes one score; LDS softmax.
__global__ __launch_bounds__(256)
void scores_simple(const float* __restrict__ q, const float* __restrict__ k,
                   float* __restrict__ P) {
    const int rid = blockIdx.x;
    const int n = rid & 255, bh = rid >> 8, h = bh & 7, b = bh >> 3;
    const int m = threadIdx.x;
    const float* qr = q + (size_t)(b * 256 + n) * 4096 + h * 512;
    const float* kr = k + (size_t)(b * 256 + m) * 4096 + h * 512;

    float s = 0.f;
    for (int d = 0; d < 512; d += 4) {
        const float4 qa = *(const float4*)(qr + d);
        const float4 ka = *(const float4*)(kr + d);
        s += qa.x * ka.x + qa.y * ka.y + qa.z * ka.z + qa.w * ka.w;
    }
    s *= 0.125f;                       // 1/sqrt(D//H) = 1/8

    __shared__ float sm[256];
    sm[m] = s;
    __syncthreads();
    float mx = -1e30f;
    for (int i = 0; i < 256; ++i) mx = fmaxf(mx, sm[i]);
    const float e = __expf(s - mx);
    __syncthreads();
    sm[m] = e;
    __syncthreads();
    float den = 0.f;
    for (int i = 0; i < 256; ++i) den += sm[i];
    P[(size_t)rid * 256 + m] = e / den;
}

// ---------------- PV: ao[b,n,h*512+d] = sum_m P[b,h,n,m] * v[b,m,h*512+d] ---
__global__ __launch_bounds__(256)
void pv_simple(const float* __restrict__ P, const u16* __restrict__ V,
               float* __restrict__ O) {
    const size_t idx = (size_t)blockIdx.x * 256 + threadIdx.x;
    const int col = (int)(idx & 4095);   // h*512 + d
    const int row = (int)(idx >> 12);    // b*256 + n
    const int h = col >> 9, b = row >> 8, n = row & 255;
    const float* Pr = P + (size_t)((b * 8 + h) * 256 + n) * 256;
    const u16* Vc = V + (size_t)(b * 256) * 4096 + col;

    float acc = 0.f;
    for (int m = 0; m < 256; ++m) acc += Pr[m] * bf2f(Vc[(size_t)m << 12]);
    O[idx] = acc;
}

// ---------------------------------------------------------------------------
extern "C" void kernel_launch(void* const* d_in, const int* in_sizes, int n_in,
                              void* d_out, int out_size, void* d_ws, size_t ws_size,
                              hipStream_t stream) {
    const float* x   = (const float*)d_in[0];
    const float* pos = (const float*)d_in[1];
    const float* wE  = (const float*)d_in[2];
    const float* bE  = (const float*)d_in[3];
    const float* wQ  = (const float*)d_in[4];
    const float* bq  = (const float*)d_in[5];
    const float* wK  = (const float*)d_in[6];
    const float* bk  = (const float*)d_in[7];
    const float* wV  = (const float*)d_in[8];
    const float* bv  = (const float*)d_in[9];
    const float* wO  = (const float*)d_in[10];
    const float* bo  = (const float*)d_in[11];

    float* out  = (float*)d_out;                    // output 0: 16,777,216 fp32
    float* Pout = out + (size_t)16777216;           // output 1: 8,388,608 fp32

    // ws layout (byte offsets, MiB): peak 256 MiB
    char* W = (char*)d_ws;
    const size_t MB = 1024 * 1024;
    u16*   xh  = (u16*)(W + 0 * MB);     // x hi          (0-32)
    u16*   xl  = (u16*)(W + 32 * MB);    // x lo          (32-64)
    u16*   Whi = (u16*)(W + 64 * MB);    // weight hi     (64-96)
    u16*   Wlo = (u16*)(W + 96 * MB);    // weight lo     (96-128)
    u16*   xeh = (u16*)(W + 128 * MB);   // xe hi         (128-160)
    u16*   xel = (u16*)(W + 160 * MB);   // xe lo         (160-192)
    float* kf  = (float*)(W + 192 * MB); // K fp32        (192-256)
    float* qf  = (float*)(W + 0 * MB);   // Q fp32 over x slabs (dead)
    float* ao  = (float*)(W + 0 * MB);   // PV out over qf (dead after scores)
    u16*   vb  = (u16*)(W + 160 * MB);   // V bf16 over xel (dead after K)
    u16*   aob = (u16*)(W + 128 * MB);   // bf16(ao) over xeh (dead after V)

    const int CVG = 16384;   // 16.7M elems / (256 thr * 4/thread)

    split2<<<CVG, 256, 0, stream>>>(x, xh, xl);
    split2<<<CVG, 256, 0, stream>>>(wE, Whi, Wlo);
    gemm3_nt<0><<<1024, 256, 0, stream>>>(xh, xl, Whi, Wlo, bE, pos,
                                          xeh, xel, nullptr);

    split2<<<CVG, 256, 0, stream>>>(wQ, Whi, Wlo);
    gemm3_nt<1><<<1024, 256, 0, stream>>>(xeh, xel, Whi, Wlo, bq, nullptr,
                                          nullptr, nullptr, qf);

    split2<<<CVG, 256, 0, stream>>>(wK, Whi, Wlo);
    gemm3_nt<1><<<1024, 256, 0, stream>>>(xeh, xel, Whi, Wlo, bk, nullptr,
                                          nullptr, nullptr, kf);

    split2<<<CVG, 256, 0, stream>>>(wV, Whi, Wlo);      // only hi used below
    gemm_nt<u16><<<1024, 256, 0, stream>>>(xeh, Whi, bv, vb);

    scores_simple<<<32768, 256, 0, stream>>>(qf, kf, Pout);
    pv_simple<<<65536, 256, 0, stream>>>(Pout, vb, ao);

    tob16<<<CVG, 256, 0, stream>>>(ao, aob);
    split2<<<CVG, 256, 0, stream>>>(wO, Whi, Wlo);      // only hi used below
    gemm_nt<float><<<1024, 256, 0, stream>>>(aob, Whi, bo, out);
}

// Round 6
// 1705.334 us; speedup vs baseline: 2.5971x; 2.5971x over previous
//
#include <hip/hip_runtime.h>
#include <hip/hip_bf16.h>

// B=16, N=256, P=8, D=512, H=8, E=4096, dh=512, scale=1/8.
// Outputs fp32: out0 [16,256,8,512] then attn_weights [16,8,256,256].
// Validated facts: d_out is fp32 (round 5); MFMA GEMM + round-1 attention
// kernels compute values bit-matching the simple fp32 pipeline (rounds 1-4
// identical absmax); ws_size >= 288 MiB (round 1 in-bounds behavior).
// Precision tiers: embed/Q/K as split-bf16 3-product MFMA (logits std ~7.6,
// peaked softmax => need near-fp32 logits); V/out/PV plain bf16 MFMA
// (out0 margin 0.0625 vs 0.19 measured in round 5).

typedef unsigned short u16;
typedef __attribute__((ext_vector_type(8))) short vbf16x8;   // 8 bf16 = 4 VGPR
typedef __attribute__((ext_vector_type(4))) float vf32x4;    // MFMA acc

#define MFMA_BF16(a, b, c) __builtin_amdgcn_mfma_f32_16x16x32_bf16(a, b, c, 0, 0, 0)

__device__ __forceinline__ u16 f2bf(float f) {
    unsigned u = __float_as_uint(f);
    u += 0x7fffu + ((u >> 16) & 1u);   // RNE
    return (u16)(u >> 16);
}
__device__ __forceinline__ float bf2f(u16 u) {
    return __uint_as_float(((unsigned)u) << 16);
}

__device__ __forceinline__ void gld16(const u16* g, u16* l) {
    // async global->LDS, 16B/lane; LDS dest = wave-uniform base + lane*16
    __builtin_amdgcn_global_load_lds((const __attribute__((address_space(1))) void*)g,
                                     (__attribute__((address_space(3))) void*)l,
                                     16, 0, 0);
}

// ---------------- fp32 -> bf16 hi/lo split ----------------------------------
__global__ __launch_bounds__(256) void split2(const float* __restrict__ s,
                                              u16* __restrict__ dh,
                                              u16* __restrict__ dl) {
    const size_t i = ((size_t)blockIdx.x * 256 + threadIdx.x) * 4;
    const float4 v = *(const float4*)(s + i);
    float vv[4] = {v.x, v.y, v.z, v.w};
#pragma unroll
    for (int j = 0; j < 4; ++j) {
        const u16 h = f2bf(vv[j]);
        dh[i + j] = h;
        dl[i + j] = f2bf(vv[j] - bf2f(h));
    }
}

// ---------------- fp32 -> bf16 (hi only) ------------------------------------
__global__ __launch_bounds__(256) void tob16(const float* __restrict__ s,
                                             u16* __restrict__ d) {
    const size_t i = ((size_t)blockIdx.x * 256 + threadIdx.x) * 4;
    const float4 v = *(const float4*)(s + i);
    d[i + 0] = f2bf(v.x); d[i + 1] = f2bf(v.y);
    d[i + 2] = f2bf(v.z); d[i + 3] = f2bf(v.w);
}

// ---------------- split-bf16 NT GEMM: C = (Ah+Al)@(Bh+Bl)^T + bias (+pos) ---
// 3-product MFMA (drops lo*lo). 128x128 tile, BK=64. Output: hi/lo bf16 pair.
template <bool ADDPOS>
__global__ __launch_bounds__(256)
void gemm3_nt(const u16* __restrict__ Ah, const u16* __restrict__ Al,
              const u16* __restrict__ Bh, const u16* __restrict__ Bl,
              const float* __restrict__ bias, const float* __restrict__ pos,
              u16* __restrict__ Chi, u16* __restrict__ Clo) {
    __shared__ __align__(16) u16 Ahs[128 * 64];
    __shared__ __align__(16) u16 Als[128 * 64];
    __shared__ __align__(16) u16 Bhs[128 * 64];
    __shared__ __align__(16) u16 Bls[128 * 64];
    const int t = threadIdx.x;
    const int lane = t & 63, w = t >> 6;
    const int wr = (w >> 1) << 6, wc = (w & 1) << 6;
    const int l15 = lane & 15, lg = lane >> 4;
    const int m0 = (blockIdx.x >> 5) << 7, n0 = (blockIdx.x & 31) << 7;

    vf32x4 acc[4][4] = {};

    for (int k0 = 0; k0 < 4096; k0 += 64) {
#pragma unroll
        for (int i = 0; i < 4; ++i) {
            const int c = t + (i << 8);           // chunk 0..1023 (16B each)
            const int row = c >> 3, c8 = (c & 7) << 3;
            const size_t goA = (((size_t)(m0 + row)) << 12) + k0 + c8;
            const size_t goB = (((size_t)(n0 + row)) << 12) + k0 + c8;
            gld16(Ah + goA, Ahs + c * 8);
            gld16(Al + goA, Als + c * 8);
            gld16(Bh + goB, Bhs + c * 8);
            gld16(Bl + goB, Bls + c * 8);
        }
        __syncthreads();
#pragma unroll
        for (int kk = 0; kk < 2; ++kk) {
            vbf16x8 ah[4], al[4], bh[4], bl[4];
#pragma unroll
            for (int m = 0; m < 4; ++m) {
                const int off = (wr + m * 16 + l15) * 64 + kk * 32 + lg * 8;
                ah[m] = *(const vbf16x8*)(Ahs + off);
                al[m] = *(const vbf16x8*)(Als + off);
            }
#pragma unroll
            for (int n = 0; n < 4; ++n) {
                const int off = (wc + n * 16 + l15) * 64 + kk * 32 + lg * 8;
                bh[n] = *(const vbf16x8*)(Bhs + off);
                bl[n] = *(const vbf16x8*)(Bls + off);
            }
#pragma unroll
            for (int m = 0; m < 4; ++m)
#pragma unroll
                for (int n = 0; n < 4; ++n) {
                    acc[m][n] = MFMA_BF16(al[m], bh[n], acc[m][n]);
                    acc[m][n] = MFMA_BF16(ah[m], bl[n], acc[m][n]);
                    acc[m][n] = MFMA_BF16(ah[m], bh[n], acc[m][n]);
                }
        }
        __syncthreads();
    }

#pragma unroll
    for (int m = 0; m < 4; ++m)
#pragma unroll
        for (int n = 0; n < 4; ++n) {
            const int col = n0 + wc + n * 16 + l15;
            const float bv = bias[col];
#pragma unroll
            for (int r = 0; r < 4; ++r) {
                const int row = m0 + wr + m * 16 + lg * 4 + r;
                float v = acc[m][n][r] + bv;
                if (ADDPOS) v += pos[((size_t)(row & 255) << 12) + col];
                const u16 hh = f2bf(v);
                Chi[((size_t)row << 12) + col] = hh;
                Clo[((size_t)row << 12) + col] = f2bf(v - bf2f(hh));
            }
        }
}

// ---------------- plain bf16 NT GEMM (V and output projections) -------------
template <typename OutT>
__global__ __launch_bounds__(256)
void gemm_nt(const u16* __restrict__ A, const u16* __restrict__ Bw,
             const float* __restrict__ bias, OutT* __restrict__ C) {
    __shared__ __align__(16) u16 As[128 * 64];
    __shared__ __align__(16) u16 Bs[128 * 64];
    const int t = threadIdx.x;
    const int lane = t & 63, w = t >> 6;
    const int wr = (w >> 1) << 6, wc = (w & 1) << 6;
    const int l15 = lane & 15, lg = lane >> 4;
    const int m0 = (blockIdx.x >> 5) << 7, n0 = (blockIdx.x & 31) << 7;

    vf32x4 acc[4][4] = {};

    for (int k0 = 0; k0 < 4096; k0 += 64) {
#pragma unroll
        for (int i = 0; i < 4; ++i) {
            const int c = t + (i << 8);
            const int row = c >> 3, c8 = (c & 7) << 3;
            gld16(A  + (((size_t)(m0 + row)) << 12) + k0 + c8, As + c * 8);
            gld16(Bw + (((size_t)(n0 + row)) << 12) + k0 + c8, Bs + c * 8);
        }
        __syncthreads();
#pragma unroll
        for (int kk = 0; kk < 2; ++kk) {
            vbf16x8 af[4], bfr[4];
#pragma unroll
            for (int m = 0; m < 4; ++m)
                af[m] = *(const vbf16x8*)(As + (wr + m * 16 + l15) * 64 + kk * 32 + lg * 8);
#pragma unroll
            for (int n = 0; n < 4; ++n)
                bfr[n] = *(const vbf16x8*)(Bs + (wc + n * 16 + l15) * 64 + kk * 32 + lg * 8);
#pragma unroll
            for (int m = 0; m < 4; ++m)
#pragma unroll
                for (int n = 0; n < 4; ++n)
                    acc[m][n] = MFMA_BF16(af[m], bfr[n], acc[m][n]);
        }
        __syncthreads();
    }

#pragma unroll
    for (int m = 0; m < 4; ++m)
#pragma unroll
        for (int n = 0; n < 4; ++n) {
            const int col = n0 + wc + n * 16 + l15;
            const float bv = bias[col];
#pragma unroll
            for (int r = 0; r < 4; ++r) {
                const int row = m0 + wr + m * 16 + lg * 4 + r;
                const float v = acc[m][n][r] + bv;
                if constexpr (sizeof(OutT) == 2)
                    C[((size_t)row << 12) + col] = f2bf(v);
                else
                    C[((size_t)row << 12) + col] = v;
            }
        }
}

// ---------------- MFMA scores + softmax (split-bf16 QK^T) -------------------
// grid = 128 (b,h) * 4 q-slabs of 64 rows; block computes 64x256 scores.
// Writes P fp32 (output 1) and P bf16 (PV input).
__global__ __launch_bounds__(256)
void attn_scores(const u16* __restrict__ qh, const u16* __restrict__ ql,
                 const u16* __restrict__ kh, const u16* __restrict__ kl,
                 float* __restrict__ Pf, u16* __restrict__ Pb) {
    const int blk = blockIdx.x;
    const int bh = blk >> 2, it = blk & 3;
    const int b = bh >> 3, h = bh & 7;
    const size_t qoff = ((size_t)(b * 256 + it * 64) << 12) + (h << 9);
    const size_t koff = ((size_t)(b * 256) << 12) + (h << 9);
    __shared__ __align__(16) u16 Qhs[64 * 64];
    __shared__ __align__(16) u16 Qls[64 * 64];
    __shared__ __align__(16) u16 Khs[256 * 64];
    __shared__ __align__(16) u16 Kls[256 * 64];
    __shared__ float red[4][64];

    const int t = threadIdx.x;
    const int lane = t & 63, w = t >> 6;
    const int l15 = lane & 15, lg = lane >> 4;

    vf32x4 acc[4][4] = {};

    for (int k0 = 0; k0 < 512; k0 += 64) {
#pragma unroll
        for (int i = 0; i < 2; ++i) {               // Q slab: 64x64 hi+lo
            const int c = t + (i << 8);
            const int row = c >> 3, c8 = (c & 7) << 3;
            gld16(qh + qoff + ((size_t)row << 12) + k0 + c8, Qhs + c * 8);
            gld16(ql + qoff + ((size_t)row << 12) + k0 + c8, Qls + c * 8);
        }
#pragma unroll
        for (int i = 0; i < 8; ++i) {               // K: 256x64 hi+lo
            const int c = t + (i << 8);
            const int row = c >> 3, c8 = (c & 7) << 3;
            gld16(kh + koff + ((size_t)row << 12) + k0 + c8, Khs + c * 8);
            gld16(kl + koff + ((size_t)row << 12) + k0 + c8, Kls + c * 8);
        }
        __syncthreads();
#pragma unroll
        for (int kk = 0; kk < 2; ++kk) {
            vbf16x8 ah[4], al[4], bhv[4], blv[4];
#pragma unroll
            for (int m = 0; m < 4; ++m) {
                const int off = (m * 16 + l15) * 64 + kk * 32 + lg * 8;
                ah[m] = *(const vbf16x8*)(Qhs + off);
                al[m] = *(const vbf16x8*)(Qls + off);
            }
#pragma unroll
            for (int n = 0; n < 4; ++n) {
                const int off = (w * 64 + n * 16 + l15) * 64 + kk * 32 + lg * 8;
                bhv[n] = *(const vbf16x8*)(Khs + off);
                blv[n] = *(const vbf16x8*)(Kls + off);
            }
#pragma unroll
            for (int m = 0; m < 4; ++m)
#pragma unroll
                for (int n = 0; n < 4; ++n) {
                    acc[m][n] = MFMA_BF16(al[m], bhv[n], acc[m][n]);
                    acc[m][n] = MFMA_BF16(ah[m], blv[n], acc[m][n]);
                    acc[m][n] = MFMA_BF16(ah[m], bhv[n], acc[m][n]);
                }
        }
        __syncthreads();
    }

#pragma unroll
    for (int m = 0; m < 4; ++m)
#pragma unroll
        for (int n = 0; n < 4; ++n) acc[m][n] *= 0.125f;

    // row max: over n lane-local, shfl over the 16-lane col group, LDS over waves
    float gm[4][4];
#pragma unroll
    for (int m = 0; m < 4; ++m)
#pragma unroll
        for (int r = 0; r < 4; ++r) {
            float v = fmaxf(fmaxf(acc[m][0][r], acc[m][1][r]),
                            fmaxf(acc[m][2][r], acc[m][3][r]));
#pragma unroll
            for (int off = 1; off < 16; off <<= 1) v = fmaxf(v, __shfl_xor(v, off));
            gm[m][r] = v;
        }
    if (l15 == 0) {
#pragma unroll
        for (int m = 0; m < 4; ++m)
#pragma unroll
            for (int r = 0; r < 4; ++r) red[w][m * 16 + lg * 4 + r] = gm[m][r];
    }
    __syncthreads();
#pragma unroll
    for (int m = 0; m < 4; ++m)
#pragma unroll
        for (int r = 0; r < 4; ++r) {
            const int row = m * 16 + lg * 4 + r;
            gm[m][r] = fmaxf(fmaxf(red[0][row], red[1][row]),
                             fmaxf(red[2][row], red[3][row]));
        }
    __syncthreads();   // protect red reuse

    // exp + row sum
    float gs[4][4];
#pragma unroll
    for (int m = 0; m < 4; ++m)
#pragma unroll
        for (int r = 0; r < 4; ++r) {
            float s = 0.f;
#pragma unroll
            for (int n = 0; n < 4; ++n) {
                const float e = __expf(acc[m][n][r] - gm[m][r]);
                acc[m][n][r] = e;
                s += e;
            }
#pragma unroll
            for (int off = 1; off < 16; off <<= 1) s += __shfl_xor(s, off);
            gs[m][r] = s;
        }
    if (l15 == 0) {
#pragma unroll
        for (int m = 0; m < 4; ++m)
#pragma unroll
            for (int r = 0; r < 4; ++r) red[w][m * 16 + lg * 4 + r] = gs[m][r];
    }
    __syncthreads();

    const size_t pbase = ((size_t)bh * 256 + it * 64) * 256;
#pragma unroll
    for (int m = 0; m < 4; ++m)
#pragma unroll
        for (int r = 0; r < 4; ++r) {
            const int row = m * 16 + lg * 4 + r;
            const float inv = 1.0f / (red[0][row] + red[1][row] +
                                      red[2][row] + red[3][row]);
#pragma unroll
            for (int n = 0; n < 4; ++n) {
                const int col = w * 64 + n * 16 + l15;
                const float p = acc[m][n][r] * inv;
                Pf[pbase + (size_t)row * 256 + col] = p;
                Pb[pbase + (size_t)row * 256 + col] = f2bf(p);
            }
        }
}

// ---------------- PV: ao[b,n,h*512+j] = sum_m P[b,h,n,m] * v[b,m,h*512+j] ---
// grid = 128 bh * 2 m-tiles * 4 n-tiles; 128x128 tile; V staged transposed.
__global__ __launch_bounds__(256)
void attn_pv(const u16* __restrict__ P, const u16* __restrict__ V,
             u16* __restrict__ O) {
    __shared__ __align__(16) u16 Ps[128 * 64];
    __shared__ __align__(16) u16 Vt[128 * 72];   // [j][m], padded stride 72
    const int t = threadIdx.x;
    const int lane = t & 63, w = t >> 6;
    const int wr = (w >> 1) << 6, wc = (w & 1) << 6;
    const int l15 = lane & 15, lg = lane >> 4;
    const int blk = blockIdx.x;
    const int bh = blk >> 3, mt = (blk >> 2) & 1, nt = blk & 3;
    const int b = bh >> 3, h = bh & 7;
    const u16* Pb = P + ((size_t)bh << 16) + ((size_t)mt << 15);
    const u16* Vb = V + ((size_t)(b * 256) << 12) + (h << 9) + (nt << 7);

    vf32x4 acc[4][4] = {};

    for (int k0 = 0; k0 < 256; k0 += 64) {
#pragma unroll
        for (int i = 0; i < 4; ++i) {               // P tile 128x64, linear
            const int c = t + (i << 8);
            const int row = c >> 3, c8 = (c & 7) << 3;
            gld16(Pb + (size_t)row * 256 + k0 + c8, Ps + c * 8);
        }
#pragma unroll
        for (int pp = 0; pp < 4; ++pp) {            // V tile 64x128, transposed
            const int kr = pp * 16 + (t >> 4);
            const int c8 = (t & 15) << 3;
            vbf16x8 vv = *(const vbf16x8*)(Vb + ((size_t)(k0 + kr) << 12) + c8);
#pragma unroll
            for (int c = 0; c < 8; ++c) Vt[(c8 + c) * 72 + kr] = (u16)vv[c];
        }
        __syncthreads();
#pragma unroll
        for (int kk = 0; kk < 2; ++kk) {
            vbf16x8 af[4], bfr[4];
#pragma unroll
            for (int m = 0; m < 4; ++m)
                af[m] = *(const vbf16x8*)(Ps + (wr + m * 16 + l15) * 64 + kk * 32 + lg * 8);
#pragma unroll
            for (int n = 0; n < 4; ++n)
                bfr[n] = *(const vbf16x8*)(Vt + (wc + n * 16 + l15) * 72 + kk * 32 + lg * 8);
#pragma unroll
            for (int m = 0; m < 4; ++m)
#pragma unroll
                for (int n = 0; n < 4; ++n)
                    acc[m][n] = MFMA_BF16(af[m], bfr[n], acc[m][n]);
        }
        __syncthreads();
    }

#pragma unroll
    for (int m = 0; m < 4; ++m)
#pragma unroll
        for (int n = 0; n < 4; ++n) {
            const int col = (h << 9) + (nt << 7) + wc + n * 16 + l15;
#pragma unroll
            for (int r = 0; r < 4; ++r) {
                const int row = b * 256 + mt * 128 + wr + m * 16 + lg * 4 + r;
                O[((size_t)row << 12) + col] = f2bf(acc[m][n][r]);
            }
        }
}

// ---------------------------------------------------------------------------
extern "C" void kernel_launch(void* const* d_in, const int* in_sizes, int n_in,
                              void* d_out, int out_size, void* d_ws, size_t ws_size,
                              hipStream_t stream) {
    const float* x   = (const float*)d_in[0];
    const float* pos = (const float*)d_in[1];
    const float* wE  = (const float*)d_in[2];
    const float* bE  = (const float*)d_in[3];
    const float* wQ  = (const float*)d_in[4];
    const float* bq  = (const float*)d_in[5];
    const float* wK  = (const float*)d_in[6];
    const float* bk  = (const float*)d_in[7];
    const float* wV  = (const float*)d_in[8];
    const float* bv  = (const float*)d_in[9];
    const float* wO  = (const float*)d_in[10];
    const float* bo  = (const float*)d_in[11];

    float* out  = (float*)d_out;                    // output 0: 16,777,216 fp32
    float* Pout = out + (size_t)16777216;           // output 1:  8,388,608 fp32

    // ws layout (MiB offsets), peak 272 MiB (<= 288 proven in round 1):
    char* W = (char*)d_ws;
    const size_t MB = 1024 * 1024;
    u16* xh  = (u16*)(W + 0 * MB);     // x hi; later qh; later ao
    u16* xl  = (u16*)(W + 32 * MB);    // x lo; later ql
    u16* Whi = (u16*)(W + 64 * MB);    // current weight hi
    u16* Wlo = (u16*)(W + 96 * MB);    // current weight lo
    u16* xeh = (u16*)(W + 128 * MB);   // xe hi
    u16* xel = (u16*)(W + 160 * MB);   // xe lo; later vb (xel dead after K)
    u16* kh  = (u16*)(W + 192 * MB);   // K hi
    u16* kl  = (u16*)(W + 224 * MB);   // K lo
    u16* Pb  = (u16*)(W + 256 * MB);   // P bf16 (16 MiB)
    u16* qh  = xh;                      // Q hi/lo over x slabs (x dead)
    u16* ql  = xl;
    u16* vb  = xel;                     // V bf16 over xe-lo
    u16* ao  = xh;                      // PV out over q (dead after scores)

    const int CVG = 16384;   // 16.7M elems / (256 thr * 4/thread)

    split2<<<CVG, 256, 0, stream>>>(x, xh, xl);
    split2<<<CVG, 256, 0, stream>>>(wE, Whi, Wlo);
    gemm3_nt<true><<<1024, 256, 0, stream>>>(xh, xl, Whi, Wlo, bE, pos, xeh, xel);

    split2<<<CVG, 256, 0, stream>>>(wQ, Whi, Wlo);
    gemm3_nt<false><<<1024, 256, 0, stream>>>(xeh, xel, Whi, Wlo, bq, nullptr, qh, ql);

    split2<<<CVG, 256, 0, stream>>>(wK, Whi, Wlo);
    gemm3_nt<false><<<1024, 256, 0, stream>>>(xeh, xel, Whi, Wlo, bk, nullptr, kh, kl);

    tob16<<<CVG, 256, 0, stream>>>(wV, Whi);
    gemm_nt<u16><<<1024, 256, 0, stream>>>(xeh, Whi, bv, vb);   // over xel

    attn_scores<<<512, 256, 0, stream>>>(qh, ql, kh, kl, Pout, Pb);
    attn_pv<<<1024, 256, 0, stream>>>(Pb, vb, ao);              // over q slabs

    tob16<<<CVG, 256, 0, stream>>>(wO, Whi);
    gemm_nt<float><<<1024, 256, 0, stream>>>(ao, Whi, bo, out);
}

// Round 7
// 1434.822 us; speedup vs baseline: 3.0868x; 1.1885x over previous
//
#include <hip/hip_runtime.h>
#include <hip/hip_bf16.h>

// B=16, N=256, P=8, D=512, H=8, E=4096, dh=512, scale=1/8. Outputs fp32.
// Round-7 numerics: f16 (11-bit mantissa) replaces split-bf16.
//   embed/Q/K: 2-product GEMM  C = (Ah+Al) @ f16(W)^T   (activation split)
//   V/O:       1-product f16 GEMM
//   scores:    1-product f16 QK^T (q,k stored single f16), fp32 softmax
// Error budget: logit err worst ~0.024 -> dP <= ~0.008 (vs >=0.02 threshold);
// out0 ~0.05 (vs 0.19). Round-6 measured 0.0625 with the coarser bf16 chain.
// T1 XCD swizzle on 1024-block GEMMs (4 tile-rows per XCD -> A-panel L2 reuse).

typedef unsigned short u16;
typedef _Float16 f16;
typedef __attribute__((ext_vector_type(8))) _Float16 v8h;    // 8 f16 = 4 VGPR
typedef __attribute__((ext_vector_type(8))) short vu16x8;    // raw 16B
typedef __attribute__((ext_vector_type(4))) float vf32x4;    // MFMA acc

#define MFMA_F16(a, b, c) __builtin_amdgcn_mfma_f32_16x16x32_f16(a, b, c, 0, 0, 0)

__device__ __forceinline__ void gld16(const void* g, void* l) {
    // async global->LDS, 16B/lane; LDS dest = wave-uniform base + lane*16
    __builtin_amdgcn_global_load_lds((const __attribute__((address_space(1))) void*)g,
                                     (__attribute__((address_space(3))) void*)l,
                                     16, 0, 0);
}

// ---------------- fp32 -> f16 hi/lo split -----------------------------------
__global__ __launch_bounds__(256) void split2h(const float* __restrict__ s,
                                               f16* __restrict__ dh,
                                               f16* __restrict__ dl) {
    const size_t i = ((size_t)blockIdx.x * 256 + threadIdx.x) * 4;
    const float4 v = *(const float4*)(s + i);
    float vv[4] = {v.x, v.y, v.z, v.w};
#pragma unroll
    for (int j = 0; j < 4; ++j) {
        const f16 h = (f16)vv[j];
        dh[i + j] = h;
        dl[i + j] = (f16)(vv[j] - (float)h);
    }
}

// ---------------- fp32 -> f16 ------------------------------------------------
__global__ __launch_bounds__(256) void tof16(const float* __restrict__ s,
                                             f16* __restrict__ d) {
    const size_t i = ((size_t)blockIdx.x * 256 + threadIdx.x) * 4;
    const float4 v = *(const float4*)(s + i);
    d[i + 0] = (f16)v.x; d[i + 1] = (f16)v.y;
    d[i + 2] = (f16)v.z; d[i + 3] = (f16)v.w;
}

// ---------------- 2-product NT GEMM: C = (Ah+Al)@B^T + bias (+pos) ----------
// 128x128 tile, BK=64, 4 waves. OUTMODE 0: +pos, write hi/lo f16 pair.
// OUTMODE 1: write single f16.
template <int OUTMODE>
__global__ __launch_bounds__(256)
void gemm2_nt(const f16* __restrict__ Ah, const f16* __restrict__ Al,
              const f16* __restrict__ Bw,
              const float* __restrict__ bias, const float* __restrict__ pos,
              f16* __restrict__ Chi, f16* __restrict__ Clo,
              f16* __restrict__ Cs) {
    __shared__ __align__(16) u16 Ahs[128 * 64];
    __shared__ __align__(16) u16 Als[128 * 64];
    __shared__ __align__(16) u16 Bs[128 * 64];
    const int t = threadIdx.x;
    const int lane = t & 63, w = t >> 6;
    const int wr = (w >> 1) << 6, wc = (w & 1) << 6;
    const int l15 = lane & 15, lg = lane >> 4;
    // XCD-chunked swizzle: XCD x owns 128 contiguous tiles (4 tile-rows)
    const int wg = ((blockIdx.x & 7) << 7) + (blockIdx.x >> 3);
    const int m0 = (wg >> 5) << 7, n0 = (wg & 31) << 7;

    vf32x4 acc[4][4] = {};

    for (int k0 = 0; k0 < 4096; k0 += 64) {
#pragma unroll
        for (int i = 0; i < 4; ++i) {
            const int c = t + (i << 8);           // chunk 0..1023 (16B each)
            const int row = c >> 3, c8 = (c & 7) << 3;
            const size_t goA = (((size_t)(m0 + row)) << 12) + k0 + c8;
            const size_t goB = (((size_t)(n0 + row)) << 12) + k0 + c8;
            gld16(Ah + goA, Ahs + c * 8);
            gld16(Al + goA, Als + c * 8);
            gld16(Bw + goB, Bs + c * 8);
        }
        __syncthreads();
#pragma unroll
        for (int kk = 0; kk < 2; ++kk) {
            v8h ah[4], al[4], bf[4];
#pragma unroll
            for (int m = 0; m < 4; ++m) {
                const int off = (wr + m * 16 + l15) * 64 + kk * 32 + lg * 8;
                ah[m] = *(const v8h*)(Ahs + off);
                al[m] = *(const v8h*)(Als + off);
            }
#pragma unroll
            for (int n = 0; n < 4; ++n)
                bf[n] = *(const v8h*)(Bs + (wc + n * 16 + l15) * 64 + kk * 32 + lg * 8);
#pragma unroll
            for (int m = 0; m < 4; ++m)
#pragma unroll
                for (int n = 0; n < 4; ++n) {
                    acc[m][n] = MFMA_F16(al[m], bf[n], acc[m][n]);
                    acc[m][n] = MFMA_F16(ah[m], bf[n], acc[m][n]);
                }
        }
        __syncthreads();
    }

#pragma unroll
    for (int m = 0; m < 4; ++m)
#pragma unroll
        for (int n = 0; n < 4; ++n) {
            const int col = n0 + wc + n * 16 + l15;
            const float bv = bias[col];
#pragma unroll
            for (int r = 0; r < 4; ++r) {
                const int row = m0 + wr + m * 16 + lg * 4 + r;
                float v = acc[m][n][r] + bv;
                if (OUTMODE == 0) {
                    v += pos[((size_t)(row & 255) << 12) + col];
                    const f16 hh = (f16)v;
                    Chi[((size_t)row << 12) + col] = hh;
                    Clo[((size_t)row << 12) + col] = (f16)(v - (float)hh);
                } else {
                    Cs[((size_t)row << 12) + col] = (f16)v;
                }
            }
        }
}

// ---------------- 1-product f16 NT GEMM (V and output projections) ----------
template <typename OutT>
__global__ __launch_bounds__(256)
void gemm1_nt(const f16* __restrict__ A, const f16* __restrict__ Bw,
              const float* __restrict__ bias, OutT* __restrict__ C) {
    __shared__ __align__(16) u16 As[128 * 64];
    __shared__ __align__(16) u16 Bs[128 * 64];
    const int t = threadIdx.x;
    const int lane = t & 63, w = t >> 6;
    const int wr = (w >> 1) << 6, wc = (w & 1) << 6;
    const int l15 = lane & 15, lg = lane >> 4;
    const int wg = ((blockIdx.x & 7) << 7) + (blockIdx.x >> 3);
    const int m0 = (wg >> 5) << 7, n0 = (wg & 31) << 7;

    vf32x4 acc[4][4] = {};

    for (int k0 = 0; k0 < 4096; k0 += 64) {
#pragma unroll
        for (int i = 0; i < 4; ++i) {
            const int c = t + (i << 8);
            const int row = c >> 3, c8 = (c & 7) << 3;
            gld16(A  + (((size_t)(m0 + row)) << 12) + k0 + c8, As + c * 8);
            gld16(Bw + (((size_t)(n0 + row)) << 12) + k0 + c8, Bs + c * 8);
        }
        __syncthreads();
#pragma unroll
        for (int kk = 0; kk < 2; ++kk) {
            v8h af[4], bf[4];
#pragma unroll
            for (int m = 0; m < 4; ++m)
                af[m] = *(const v8h*)(As + (wr + m * 16 + l15) * 64 + kk * 32 + lg * 8);
#pragma unroll
            for (int n = 0; n < 4; ++n)
                bf[n] = *(const v8h*)(Bs + (wc + n * 16 + l15) * 64 + kk * 32 + lg * 8);
#pragma unroll
            for (int m = 0; m < 4; ++m)
#pragma unroll
                for (int n = 0; n < 4; ++n)
                    acc[m][n] = MFMA_F16(af[m], bf[n], acc[m][n]);
        }
        __syncthreads();
    }

#pragma unroll
    for (int m = 0; m < 4; ++m)
#pragma unroll
        for (int n = 0; n < 4; ++n) {
            const int col = n0 + wc + n * 16 + l15;
            const float bv = bias[col];
#pragma unroll
            for (int r = 0; r < 4; ++r) {
                const int row = m0 + wr + m * 16 + lg * 4 + r;
                const float v = acc[m][n][r] + bv;
                if constexpr (sizeof(OutT) == 2)
                    C[((size_t)row << 12) + col] = (OutT)v;
                else
                    C[((size_t)row << 12) + col] = v;
            }
        }
}

// ---------------- f16 scores + softmax -> P fp32 (out1) + P f16 (PV) --------
// grid = 128 (b,h) * 4 q-slabs of 64 rows; block computes 64x256 scores.
__global__ __launch_bounds__(256)
void attn_scores(const f16* __restrict__ q, const f16* __restrict__ k,
                 float* __restrict__ Pf, f16* __restrict__ Pb) {
    const int blk = blockIdx.x;
    const int bh = blk >> 2, it = blk & 3;
    const int b = bh >> 3, h = bh & 7;
    const size_t qoff = ((size_t)(b * 256 + it * 64) << 12) + (h << 9);
    const size_t koff = ((size_t)(b * 256) << 12) + (h << 9);
    __shared__ __align__(16) u16 Qs[64 * 64];
    __shared__ __align__(16) u16 Ks[256 * 64];
    __shared__ float red[4][64];

    const int t = threadIdx.x;
    const int lane = t & 63, w = t >> 6;
    const int l15 = lane & 15, lg = lane >> 4;

    vf32x4 acc[4][4] = {};

    for (int k0 = 0; k0 < 512; k0 += 64) {
#pragma unroll
        for (int i = 0; i < 2; ++i) {               // Q slab: 64x64
            const int c = t + (i << 8);
            const int row = c >> 3, c8 = (c & 7) << 3;
            gld16(q + qoff + ((size_t)row << 12) + k0 + c8, Qs + c * 8);
        }
#pragma unroll
        for (int i = 0; i < 8; ++i) {               // K: 256x64
            const int c = t + (i << 8);
            const int row = c >> 3, c8 = (c & 7) << 3;
            gld16(k + koff + ((size_t)row << 12) + k0 + c8, Ks + c * 8);
        }
        __syncthreads();
#pragma unroll
        for (int kk = 0; kk < 2; ++kk) {
            v8h af[4], bf[4];
#pragma unroll
            for (int m = 0; m < 4; ++m)
                af[m] = *(const v8h*)(Qs + (m * 16 + l15) * 64 + kk * 32 + lg * 8);
#pragma unroll
            for (int n = 0; n < 4; ++n)
                bf[n] = *(const v8h*)(Ks + (w * 64 + n * 16 + l15) * 64 + kk * 32 + lg * 8);
#pragma unroll
            for (int m = 0; m < 4; ++m)
#pragma unroll
                for (int n = 0; n < 4; ++n)
                    acc[m][n] = MFMA_F16(af[m], bf[n], acc[m][n]);
        }
        __syncthreads();
    }

#pragma unroll
    for (int m = 0; m < 4; ++m)
#pragma unroll
        for (int n = 0; n < 4; ++n) acc[m][n] *= 0.125f;

    // row max: lane-local over n, shfl over 16-lane col group, LDS over waves
    float gm[4][4];
#pragma unroll
    for (int m = 0; m < 4; ++m)
#pragma unroll
        for (int r = 0; r < 4; ++r) {
            float v = fmaxf(fmaxf(acc[m][0][r], acc[m][1][r]),
                            fmaxf(acc[m][2][r], acc[m][3][r]));
#pragma unroll
            for (int off = 1; off < 16; off <<= 1) v = fmaxf(v, __shfl_xor(v, off));
            gm[m][r] = v;
        }
    if (l15 == 0) {
#pragma unroll
        for (int m = 0; m < 4; ++m)
#pragma unroll
            for (int r = 0; r < 4; ++r) red[w][m * 16 + lg * 4 + r] = gm[m][r];
    }
    __syncthreads();
#pragma unroll
    for (int m = 0; m < 4; ++m)
#pragma unroll
        for (int r = 0; r < 4; ++r) {
            const int row = m * 16 + lg * 4 + r;
            gm[m][r] = fmaxf(fmaxf(red[0][row], red[1][row]),
                             fmaxf(red[2][row], red[3][row]));
        }
    __syncthreads();   // protect red reuse

    // exp + row sum
    float gs[4][4];
#pragma unroll
    for (int m = 0; m < 4; ++m)
#pragma unroll
        for (int r = 0; r < 4; ++r) {
            float s = 0.f;
#pragma unroll
            for (int n = 0; n < 4; ++n) {
                const float e = __expf(acc[m][n][r] - gm[m][r]);
                acc[m][n][r] = e;
                s += e;
            }
#pragma unroll
            for (int off = 1; off < 16; off <<= 1) s += __shfl_xor(s, off);
            gs[m][r] = s;
        }
    if (l15 == 0) {
#pragma unroll
        for (int m = 0; m < 4; ++m)
#pragma unroll
            for (int r = 0; r < 4; ++r) red[w][m * 16 + lg * 4 + r] = gs[m][r];
    }
    __syncthreads();

    const size_t pbase = ((size_t)bh * 256 + it * 64) * 256;
#pragma unroll
    for (int m = 0; m < 4; ++m)
#pragma unroll
        for (int r = 0; r < 4; ++r) {
            const int row = m * 16 + lg * 4 + r;
            const float inv = 1.0f / (red[0][row] + red[1][row] +
                                      red[2][row] + red[3][row]);
#pragma unroll
            for (int n = 0; n < 4; ++n) {
                const int col = w * 64 + n * 16 + l15;
                const float p = acc[m][n][r] * inv;
                Pf[pbase + (size_t)row * 256 + col] = p;
                Pb[pbase + (size_t)row * 256 + col] = (f16)p;
            }
        }
}

// ---------------- PV: ao[b,n,h*512+j] = sum_m P[b,h,n,m] * v[b,m,h*512+j] ---
// grid = 128 bh * 2 m-tiles * 4 n-tiles; 128x128 tile; V staged transposed.
__global__ __launch_bounds__(256)
void attn_pv(const f16* __restrict__ P, const f16* __restrict__ V,
             f16* __restrict__ O) {
    __shared__ __align__(16) u16 Ps[128 * 64];
    __shared__ __align__(16) u16 Vt[128 * 72];   // [j][m], padded stride 72
    const int t = threadIdx.x;
    const int lane = t & 63, w = t >> 6;
    const int wr = (w >> 1) << 6, wc = (w & 1) << 6;
    const int l15 = lane & 15, lg = lane >> 4;
    const int blk = blockIdx.x;
    const int bh = blk >> 3, mt = (blk >> 2) & 1, nt = blk & 3;
    const int b = bh >> 3, h = bh & 7;
    const f16* Pbp = P + ((size_t)bh << 16) + ((size_t)mt << 15);
    const u16* Vb = (const u16*)V + ((size_t)(b * 256) << 12) + (h << 9) + (nt << 7);

    vf32x4 acc[4][4] = {};

    for (int k0 = 0; k0 < 256; k0 += 64) {
#pragma unroll
        for (int i = 0; i < 4; ++i) {               // P tile 128x64, linear
            const int c = t + (i << 8);
            const int row = c >> 3, c8 = (c & 7) << 3;
            gld16(Pbp + (size_t)row * 256 + k0 + c8, Ps + c * 8);
        }
#pragma unroll
        for (int pp = 0; pp < 4; ++pp) {            // V tile 64x128, transposed
            const int kr = pp * 16 + (t >> 4);
            const int c8 = (t & 15) << 3;
            vu16x8 vv = *(const vu16x8*)(Vb + ((size_t)(k0 + kr) << 12) + c8);
#pragma unroll
            for (int c = 0; c < 8; ++c) Vt[(c8 + c) * 72 + kr] = (u16)vv[c];
        }
        __syncthreads();
#pragma unroll
        for (int kk = 0; kk < 2; ++kk) {
            v8h af[4], bf[4];
#pragma unroll
            for (int m = 0; m < 4; ++m)
                af[m] = *(const v8h*)(Ps + (wr + m * 16 + l15) * 64 + kk * 32 + lg * 8);
#pragma unroll
            for (int n = 0; n < 4; ++n)
                bf[n] = *(const v8h*)(Vt + (wc + n * 16 + l15) * 72 + kk * 32 + lg * 8);
#pragma unroll
            for (int m = 0; m < 4; ++m)
#pragma unroll
                for (int n = 0; n < 4; ++n)
                    acc[m][n] = MFMA_F16(af[m], bf[n], acc[m][n]);
        }
        __syncthreads();
    }

#pragma unroll
    for (int m = 0; m < 4; ++m)
#pragma unroll
        for (int n = 0; n < 4; ++n) {
            const int col = (h << 9) + (nt << 7) + wc + n * 16 + l15;
#pragma unroll
            for (int r = 0; r < 4; ++r) {
                const int row = b * 256 + mt * 128 + wr + m * 16 + lg * 4 + r;
                O[((size_t)row << 12) + col] = (f16)acc[m][n][r];
            }
        }
}

// ---------------------------------------------------------------------------
extern "C" void kernel_launch(void* const* d_in, const int* in_sizes, int n_in,
                              void* d_out, int out_size, void* d_ws, size_t ws_size,
                              hipStream_t stream) {
    const float* x   = (const float*)d_in[0];
    const float* pos = (const float*)d_in[1];
    const float* wE  = (const float*)d_in[2];
    const float* bE  = (const float*)d_in[3];
    const float* wQ  = (const float*)d_in[4];
    const float* bq  = (const float*)d_in[5];
    const float* wK  = (const float*)d_in[6];
    const float* bk  = (const float*)d_in[7];
    const float* wV  = (const float*)d_in[8];
    const float* bv  = (const float*)d_in[9];
    const float* wO  = (const float*)d_in[10];
    const float* bo  = (const float*)d_in[11];

    float* out  = (float*)d_out;                    // output 0: 16,777,216 fp32
    float* Pout = out + (size_t)16777216;           // output 1:  8,388,608 fp32

    // ws layout (MiB offsets), peak 272 MiB (round 1 proved >= 288 usable)
    char* W = (char*)d_ws;
    const size_t MB = 1024 * 1024;
    f16* xh    = (f16*)(W + 0 * MB);     // x hi; later ao (x dead post-embed)
    f16* xl    = (f16*)(W + 32 * MB);    // x lo
    f16* wslab = (f16*)(W + 64 * MB);    // current weight f16
    f16* xeh   = (f16*)(W + 96 * MB);    // xe hi
    f16* xel   = (f16*)(W + 128 * MB);   // xe lo
    f16* qs    = (f16*)(W + 160 * MB);   // Q f16
    f16* ks    = (f16*)(W + 192 * MB);   // K f16
    f16* vs    = (f16*)(W + 224 * MB);   // V f16
    f16* Pb    = (f16*)(W + 256 * MB);   // P f16 (16 MiB)
    f16* ao    = xh;                     // PV result over x-hi

    const int CVG = 16384;   // 16.7M elems / (256 thr * 4/thread)

    split2h<<<CVG, 256, 0, stream>>>(x, xh, xl);
    tof16<<<CVG, 256, 0, stream>>>(wE, wslab);
    gemm2_nt<0><<<1024, 256, 0, stream>>>(xh, xl, wslab, bE, pos,
                                          xeh, xel, nullptr);

    tof16<<<CVG, 256, 0, stream>>>(wQ, wslab);
    gemm2_nt<1><<<1024, 256, 0, stream>>>(xeh, xel, wslab, bq, nullptr,
                                          nullptr, nullptr, qs);

    tof16<<<CVG, 256, 0, stream>>>(wK, wslab);
    gemm2_nt<1><<<1024, 256, 0, stream>>>(xeh, xel, wslab, bk, nullptr,
                                          nullptr, nullptr, ks);

    tof16<<<CVG, 256, 0, stream>>>(wV, wslab);
    gemm1_nt<f16><<<1024, 256, 0, stream>>>(xeh, wslab, bv, vs);

    attn_scores<<<512, 256, 0, stream>>>(qs, ks, Pout, Pb);
    attn_pv<<<1024, 256, 0, stream>>>(Pb, vs, ao);

    tof16<<<CVG, 256, 0, stream>>>(wO, wslab);
    gemm1_nt<float><<<1024, 256, 0, stream>>>(ao, wslab, bo, out);
}

// Round 8
// 1175.855 us; speedup vs baseline: 3.7666x; 1.2202x over previous
//
#include <hip/hip_runtime.h>
#include <hip/hip_bf16.h>

// B=16, N=256, P=8, D=512, H=8, E=4096, dh=512, scale=1/8. Outputs fp32.
// Round-8: ALL GEMMs single-product f16 (round 7 proved q/k stored as f16 +
// 1-product QK^T passes; xe hi/lo split only added ~4e-4 logit accuracy,
// below the already-present q/k rounding term). absmax 0.0625 across rounds
// 5-7 = 1 ulp of bf16 at 9.56 (harness grid floor) => precision headroom.
// Structure: 128x128 tile, BK=64, global_load_lds w16, XCD-chunked swizzle.
// Per regime-gate (learn_hip m228d/m230): no swizzle/pipelining at 2-phase.

typedef unsigned short u16;
typedef _Float16 f16;
typedef __attribute__((ext_vector_type(8))) _Float16 v8h;    // 8 f16 = 4 VGPR
typedef __attribute__((ext_vector_type(8))) short vu16x8;    // raw 16B
typedef __attribute__((ext_vector_type(4))) float vf32x4;    // MFMA acc

#define MFMA_F16(a, b, c) __builtin_amdgcn_mfma_f32_16x16x32_f16(a, b, c, 0, 0, 0)

__device__ __forceinline__ void gld16(const void* g, void* l) {
    // async global->LDS, 16B/lane; LDS dest = wave-uniform base + lane*16
    __builtin_amdgcn_global_load_lds((const __attribute__((address_space(1))) void*)g,
                                     (__attribute__((address_space(3))) void*)l,
                                     16, 0, 0);
}

// ---------------- fp32 -> f16 ------------------------------------------------
__global__ __launch_bounds__(256) void tof16(const float* __restrict__ s,
                                             f16* __restrict__ d) {
    const size_t i = ((size_t)blockIdx.x * 256 + threadIdx.x) * 4;
    const float4 v = *(const float4*)(s + i);
    d[i + 0] = (f16)v.x; d[i + 1] = (f16)v.y;
    d[i + 2] = (f16)v.z; d[i + 3] = (f16)v.w;
}

// ---------------- f16 NT GEMM: C = A@B^T + bias (+pos) ----------------------
// 128x128 tile, BK=64, 4 waves (64x64 each, 4x4 MFMA frags), m97 structure.
// MODE 0: +bias +pos -> f16 ; MODE 1: +bias -> f16 ; MODE 2: +bias -> fp32.
template <int MODE>
__global__ __launch_bounds__(256)
void gemm1_nt(const f16* __restrict__ A, const f16* __restrict__ Bw,
              const float* __restrict__ bias, const float* __restrict__ pos,
              f16* __restrict__ Ch, float* __restrict__ Cf) {
    __shared__ __align__(16) u16 As[128 * 64];
    __shared__ __align__(16) u16 Bs[128 * 64];
    const int t = threadIdx.x;
    const int lane = t & 63, w = t >> 6;
    const int wr = (w >> 1) << 6, wc = (w & 1) << 6;
    const int l15 = lane & 15, lg = lane >> 4;
    // XCD-chunked swizzle: each XCD owns 128 contiguous tiles (4 tile-rows)
    const int wg = ((blockIdx.x & 7) << 7) + (blockIdx.x >> 3);
    const int m0 = (wg >> 5) << 7, n0 = (wg & 31) << 7;

    vf32x4 acc[4][4] = {};

    for (int k0 = 0; k0 < 4096; k0 += 64) {
#pragma unroll
        for (int i = 0; i < 4; ++i) {
            const int c = t + (i << 8);           // chunk 0..1023 (16B each)
            const int row = c >> 3, c8 = (c & 7) << 3;
            gld16(A  + (((size_t)(m0 + row)) << 12) + k0 + c8, As + c * 8);
            gld16(Bw + (((size_t)(n0 + row)) << 12) + k0 + c8, Bs + c * 8);
        }
        __syncthreads();
#pragma unroll
        for (int kk = 0; kk < 2; ++kk) {
            v8h af[4], bf[4];
#pragma unroll
            for (int m = 0; m < 4; ++m)
                af[m] = *(const v8h*)(As + (wr + m * 16 + l15) * 64 + kk * 32 + lg * 8);
#pragma unroll
            for (int n = 0; n < 4; ++n)
                bf[n] = *(const v8h*)(Bs + (wc + n * 16 + l15) * 64 + kk * 32 + lg * 8);
#pragma unroll
            for (int m = 0; m < 4; ++m)
#pragma unroll
                for (int n = 0; n < 4; ++n)
                    acc[m][n] = MFMA_F16(af[m], bf[n], acc[m][n]);
        }
        __syncthreads();
    }

#pragma unroll
    for (int m = 0; m < 4; ++m)
#pragma unroll
        for (int n = 0; n < 4; ++n) {
            const int col = n0 + wc + n * 16 + l15;
            const float bv = bias[col];
#pragma unroll
            for (int r = 0; r < 4; ++r) {
                const int row = m0 + wr + m * 16 + lg * 4 + r;
                float v = acc[m][n][r] + bv;
                if (MODE == 0) v += pos[((size_t)(row & 255) << 12) + col];
                if (MODE == 2)
                    Cf[((size_t)row << 12) + col] = v;
                else
                    Ch[((size_t)row << 12) + col] = (f16)v;
            }
        }
}

// ---------------- f16 scores + softmax -> P fp32 (out1) + P f16 (PV) --------
// grid = 128 (b,h) * 4 q-slabs of 64 rows; block computes 64x256 scores.
__global__ __launch_bounds__(256)
void attn_scores(const f16* __restrict__ q, const f16* __restrict__ k,
                 float* __restrict__ Pf, f16* __restrict__ Pb) {
    const int blk = blockIdx.x;
    const int bh = blk >> 2, it = blk & 3;
    const int b = bh >> 3, h = bh & 7;
    const size_t qoff = ((size_t)(b * 256 + it * 64) << 12) + (h << 9);
    const size_t koff = ((size_t)(b * 256) << 12) + (h << 9);
    __shared__ __align__(16) u16 Qs[64 * 64];
    __shared__ __align__(16) u16 Ks[256 * 64];
    __shared__ float red[4][64];

    const int t = threadIdx.x;
    const int lane = t & 63, w = t >> 6;
    const int l15 = lane & 15, lg = lane >> 4;

    vf32x4 acc[4][4] = {};

    for (int k0 = 0; k0 < 512; k0 += 64) {
#pragma unroll
        for (int i = 0; i < 2; ++i) {               // Q slab: 64x64
            const int c = t + (i << 8);
            const int row = c >> 3, c8 = (c & 7) << 3;
            gld16(q + qoff + ((size_t)row << 12) + k0 + c8, Qs + c * 8);
        }
#pragma unroll
        for (int i = 0; i < 8; ++i) {               // K: 256x64
            const int c = t + (i << 8);
            const int row = c >> 3, c8 = (c & 7) << 3;
            gld16(k + koff + ((size_t)row << 12) + k0 + c8, Ks + c * 8);
        }
        __syncthreads();
#pragma unroll
        for (int kk = 0; kk < 2; ++kk) {
            v8h af[4], bf[4];
#pragma unroll
            for (int m = 0; m < 4; ++m)
                af[m] = *(const v8h*)(Qs + (m * 16 + l15) * 64 + kk * 32 + lg * 8);
#pragma unroll
            for (int n = 0; n < 4; ++n)
                bf[n] = *(const v8h*)(Ks + (w * 64 + n * 16 + l15) * 64 + kk * 32 + lg * 8);
#pragma unroll
            for (int m = 0; m < 4; ++m)
#pragma unroll
                for (int n = 0; n < 4; ++n)
                    acc[m][n] = MFMA_F16(af[m], bf[n], acc[m][n]);
        }
        __syncthreads();
    }

#pragma unroll
    for (int m = 0; m < 4; ++m)
#pragma unroll
        for (int n = 0; n < 4; ++n) acc[m][n] *= 0.125f;

    // row max: lane-local over n, shfl over 16-lane col group, LDS over waves
    float gm[4][4];
#pragma unroll
    for (int m = 0; m < 4; ++m)
#pragma unroll
        for (int r = 0; r < 4; ++r) {
            float v = fmaxf(fmaxf(acc[m][0][r], acc[m][1][r]),
                            fmaxf(acc[m][2][r], acc[m][3][r]));
#pragma unroll
            for (int off = 1; off < 16; off <<= 1) v = fmaxf(v, __shfl_xor(v, off));
            gm[m][r] = v;
        }
    if (l15 == 0) {
#pragma unroll
        for (int m = 0; m < 4; ++m)
#pragma unroll
            for (int r = 0; r < 4; ++r) red[w][m * 16 + lg * 4 + r] = gm[m][r];
    }
    __syncthreads();
#pragma unroll
    for (int m = 0; m < 4; ++m)
#pragma unroll
        for (int r = 0; r < 4; ++r) {
            const int row = m * 16 + lg * 4 + r;
            gm[m][r] = fmaxf(fmaxf(red[0][row], red[1][row]),
                             fmaxf(red[2][row], red[3][row]));
        }
    __syncthreads();   // protect red reuse

    // exp + row sum
    float gs[4][4];
#pragma unroll
    for (int m = 0; m < 4; ++m)
#pragma unroll
        for (int r = 0; r < 4; ++r) {
            float s = 0.f;
#pragma unroll
            for (int n = 0; n < 4; ++n) {
                const float e = __expf(acc[m][n][r] - gm[m][r]);
                acc[m][n][r] = e;
                s += e;
            }
#pragma unroll
            for (int off = 1; off < 16; off <<= 1) s += __shfl_xor(s, off);
            gs[m][r] = s;
        }
    if (l15 == 0) {
#pragma unroll
        for (int m = 0; m < 4; ++m)
#pragma unroll
            for (int r = 0; r < 4; ++r) red[w][m * 16 + lg * 4 + r] = gs[m][r];
    }
    __syncthreads();

    const size_t pbase = ((size_t)bh * 256 + it * 64) * 256;
#pragma unroll
    for (int m = 0; m < 4; ++m)
#pragma unroll
        for (int r = 0; r < 4; ++r) {
            const int row = m * 16 + lg * 4 + r;
            const float inv = 1.0f / (red[0][row] + red[1][row] +
                                      red[2][row] + red[3][row]);
#pragma unroll
            for (int n = 0; n < 4; ++n) {
                const int col = w * 64 + n * 16 + l15;
                const float p = acc[m][n][r] * inv;
                Pf[pbase + (size_t)row * 256 + col] = p;
                Pb[pbase + (size_t)row * 256 + col] = (f16)p;
            }
        }
}

// ---------------- PV: ao[b,n,h*512+j] = sum_m P[b,h,n,m] * v[b,m,h*512+j] ---
// grid = 128 bh * 2 m-tiles * 4 n-tiles; 128x128 tile; V staged transposed.
__global__ __launch_bounds__(256)
void attn_pv(const f16* __restrict__ P, const f16* __restrict__ V,
             f16* __restrict__ O) {
    __shared__ __align__(16) u16 Ps[128 * 64];
    __shared__ __align__(16) u16 Vt[128 * 72];   // [j][m], padded stride 72
    const int t = threadIdx.x;
    const int lane = t & 63, w = t >> 6;
    const int wr = (w >> 1) << 6, wc = (w & 1) << 6;
    const int l15 = lane & 15, lg = lane >> 4;
    const int blk = blockIdx.x;
    const int bh = blk >> 3, mt = (blk >> 2) & 1, nt = blk & 3;
    const int b = bh >> 3, h = bh & 7;
    const f16* Pbp = P + ((size_t)bh << 16) + ((size_t)mt << 15);
    const u16* Vb = (const u16*)V + ((size_t)(b * 256) << 12) + (h << 9) + (nt << 7);

    vf32x4 acc[4][4] = {};

    for (int k0 = 0; k0 < 256; k0 += 64) {
#pragma unroll
        for (int i = 0; i < 4; ++i) {               // P tile 128x64, linear
            const int c = t + (i << 8);
            const int row = c >> 3, c8 = (c & 7) << 3;
            gld16(Pbp + (size_t)row * 256 + k0 + c8, Ps + c * 8);
        }
#pragma unroll
        for (int pp = 0; pp < 4; ++pp) {            // V tile 64x128, transposed
            const int kr = pp * 16 + (t >> 4);
            const int c8 = (t & 15) << 3;
            vu16x8 vv = *(const vu16x8*)(Vb + ((size_t)(k0 + kr) << 12) + c8);
#pragma unroll
            for (int c = 0; c < 8; ++c) Vt[(c8 + c) * 72 + kr] = (u16)vv[c];
        }
        __syncthreads();
#pragma unroll
        for (int kk = 0; kk < 2; ++kk) {
            v8h af[4], bf[4];
#pragma unroll
            for (int m = 0; m < 4; ++m)
                af[m] = *(const v8h*)(Ps + (wr + m * 16 + l15) * 64 + kk * 32 + lg * 8);
#pragma unroll
            for (int n = 0; n < 4; ++n)
                bf[n] = *(const v8h*)(Vt + (wc + n * 16 + l15) * 72 + kk * 32 + lg * 8);
#pragma unroll
            for (int m = 0; m < 4; ++m)
#pragma unroll
                for (int n = 0; n < 4; ++n)
                    acc[m][n] = MFMA_F16(af[m], bf[n], acc[m][n]);
        }
        __syncthreads();
    }

#pragma unroll
    for (int m = 0; m < 4; ++m)
#pragma unroll
        for (int n = 0; n < 4; ++n) {
            const int col = (h << 9) + (nt << 7) + wc + n * 16 + l15;
#pragma unroll
            for (int r = 0; r < 4; ++r) {
                const int row = b * 256 + mt * 128 + wr + m * 16 + lg * 4 + r;
                O[((size_t)row << 12) + col] = (f16)acc[m][n][r];
            }
        }
}

// ---------------------------------------------------------------------------
extern "C" void kernel_launch(void* const* d_in, const int* in_sizes, int n_in,
                              void* d_out, int out_size, void* d_ws, size_t ws_size,
                              hipStream_t stream) {
    const float* x   = (const float*)d_in[0];
    const float* pos = (const float*)d_in[1];
    const float* wE  = (const float*)d_in[2];
    const float* bE  = (const float*)d_in[3];
    const float* wQ  = (const float*)d_in[4];
    const float* bq  = (const float*)d_in[5];
    const float* wK  = (const float*)d_in[6];
    const float* bk  = (const float*)d_in[7];
    const float* wV  = (const float*)d_in[8];
    const float* bv  = (const float*)d_in[9];
    const float* wO  = (const float*)d_in[10];
    const float* bo  = (const float*)d_in[11];

    float* out  = (float*)d_out;                    // output 0: 16,777,216 fp32
    float* Pout = out + (size_t)16777216;           // output 1:  8,388,608 fp32

    // ws layout (MiB offsets), peak 208 MiB
    char* W = (char*)d_ws;
    const size_t MB = 1024 * 1024;
    f16* xf    = (f16*)(W + 0 * MB);     // x f16; later ao (x dead post-embed)
    f16* wslab = (f16*)(W + 32 * MB);    // current weight f16
    f16* xe    = (f16*)(W + 64 * MB);    // embedded activations f16
    f16* qs    = (f16*)(W + 96 * MB);    // Q f16
    f16* ks    = (f16*)(W + 128 * MB);   // K f16
    f16* vs    = (f16*)(W + 160 * MB);   // V f16
    f16* Pb    = (f16*)(W + 192 * MB);   // P f16 (16 MiB)
    f16* ao    = xf;                     // PV result over x (dead)

    const int CVG = 16384;   // 16.7M elems / (256 thr * 4/thread)

    tof16<<<CVG, 256, 0, stream>>>(x, xf);
    tof16<<<CVG, 256, 0, stream>>>(wE, wslab);
    gemm1_nt<0><<<1024, 256, 0, stream>>>(xf, wslab, bE, pos, xe, nullptr);

    tof16<<<CVG, 256, 0, stream>>>(wQ, wslab);
    gemm1_nt<1><<<1024, 256, 0, stream>>>(xe, wslab, bq, nullptr, qs, nullptr);

    tof16<<<CVG, 256, 0, stream>>>(wK, wslab);
    gemm1_nt<1><<<1024, 256, 0, stream>>>(xe, wslab, bk, nullptr, ks, nullptr);

    tof16<<<CVG, 256, 0, stream>>>(wV, wslab);
    gemm1_nt<1><<<1024, 256, 0, stream>>>(xe, wslab, bv, nullptr, vs, nullptr);

    attn_scores<<<512, 256, 0, stream>>>(qs, ks, Pout, Pb);
    attn_pv<<<1024, 256, 0, stream>>>(Pb, vs, ao);

    tof16<<<CVG, 256, 0, stream>>>(wO, wslab);
    gemm1_nt<2><<<1024, 256, 0, stream>>>(ao, wslab, bo, nullptr, nullptr, out);
}

// Round 9
// 866.875 us; speedup vs baseline: 5.1091x; 1.3564x over previous
//
#include <hip/hip_runtime.h>
#include <hip/hip_bf16.h>

// B=16, N=256, P=8, D=512, H=8, E=4096, dh=512, scale=1/8. Outputs fp32.
// Round 9: GEMMs moved to 256x256/BK=64/8-wave pipelined schedule:
//   - 2 K-tile LDS dbuf (128 KiB), stage-issue BEFORE wait, counted vmcnt(8)
//   - T2 XOR swizzle (chunk ^= row&7), both-sides (pre-swizzled global src
//     for global_load_lds + swizzled ds_read)  [rule #21]
//   - raw s_barrier + asm waitcnt (2 barriers/K-tile), setprio on MFMA
// Numerics unchanged from round 8 (all-f16 1-product, absmax 0.0625 = grid
// floor). Scores/PV/converts unchanged.

typedef unsigned short u16;
typedef _Float16 f16;
typedef __attribute__((ext_vector_type(8))) _Float16 v8h;    // 8 f16 = 4 VGPR
typedef __attribute__((ext_vector_type(8))) short vu16x8;    // raw 16B
typedef __attribute__((ext_vector_type(4))) float vf32x4;    // MFMA acc

#define MFMA_F16(a, b, c) __builtin_amdgcn_mfma_f32_16x16x32_f16(a, b, c, 0, 0, 0)

__device__ __forceinline__ void gld16(const void* g, void* l) {
    // async global->LDS, 16B/lane; LDS dest = wave-uniform base + lane*16
    __builtin_amdgcn_global_load_lds((const __attribute__((address_space(1))) void*)g,
                                     (__attribute__((address_space(3))) void*)l,
                                     16, 0, 0);
}

// ---------------- fp32 -> f16 ------------------------------------------------
__global__ __launch_bounds__(256) void tof16(const float* __restrict__ s,
                                             f16* __restrict__ d) {
    const size_t i = ((size_t)blockIdx.x * 256 + threadIdx.x) * 4;
    const float4 v = *(const float4*)(s + i);
    d[i + 0] = (f16)v.x; d[i + 1] = (f16)v.y;
    d[i + 2] = (f16)v.z; d[i + 3] = (f16)v.w;
}

// ---------------- 256^2 pipelined f16 NT GEMM: C = A@B^T + bias (+pos) ------
// 512 thr = 8 waves (2M x 4N), per-wave 128x64 out = 8x4 frags. BK=64.
// MODE 0: +bias +pos -> f16 ; MODE 1: +bias -> f16 ; MODE 2: +bias -> fp32.
template <int MODE>
__global__ __launch_bounds__(512, 2)
void gemm8_nt(const f16* __restrict__ A, const f16* __restrict__ Bw,
              const float* __restrict__ bias, const float* __restrict__ pos,
              f16* __restrict__ Ch, float* __restrict__ Cf) {
    __shared__ __align__(16) u16 sA[2][16384];   // 256 rows x 64 f16, swizzled
    __shared__ __align__(16) u16 sB[2][16384];
    const int t = threadIdx.x;
    const int lane = t & 63, w = t >> 6;
    const int wm = w >> 2, wn = w & 3;           // 2 x 4 wave grid
    const int l15 = lane & 15, lg = lane >> 4;
    // XCD-chunked block swizzle (256 blocks, 32 per XCD = 2 tile-rows)
    const int wg = ((blockIdx.x & 7) << 5) + (blockIdx.x >> 3);
    const int m0 = (wg >> 4) << 8, n0 = (wg & 15) << 8;

    // staging source: LDS chunk c (16B) holds global (row=c>>3, colchunk=(c&7)^(row&7))
    int srow[4], scol[4];
#pragma unroll
    for (int i = 0; i < 4; ++i) {
        const int c = t + (i << 9);
        srow[i] = c >> 3;
        scol[i] = (((c & 7) ^ (srow[i] & 7)) << 3);    // f16-element offset
    }
    // ds_read bases
    const int rA = (wm << 7) + l15;              // A row (within 256)
    const int rB = (wn << 6) + l15;              // B row (within 256)
    const int xA = rA & 7, xB = rB & 7;          // swizzle keys (row&7)

    vf32x4 acc[8][4] = {};

#define STAGE(buf, k0) do {                                                    \
    _Pragma("unroll")                                                          \
    for (int i = 0; i < 4; ++i) {                                              \
        const int c = t + (i << 9);                                            \
        gld16(A  + (((size_t)(m0 + srow[i])) << 12) + (k0) + scol[i],          \
              &sA[buf][c * 8]);                                                \
    }                                                                          \
    _Pragma("unroll")                                                          \
    for (int i = 0; i < 4; ++i) {                                              \
        const int c = t + (i << 9);                                            \
        gld16(Bw + (((size_t)(n0 + srow[i])) << 12) + (k0) + scol[i],          \
              &sB[buf][c * 8]);                                                \
    }                                                                          \
} while (0)

    STAGE(0, 0);                                 // prologue: tile 0

    for (int kt = 0; kt < 64; ++kt) {
        const int cb = kt & 1;
        if (kt < 63) {
            STAGE(cb ^ 1, (kt + 1) << 6);        // issue t+1 BEFORE the wait
            asm volatile("s_waitcnt vmcnt(8)" ::: "memory");  // tile t landed
        } else {
            asm volatile("s_waitcnt vmcnt(0)" ::: "memory");
        }
        __builtin_amdgcn_s_barrier();            // all threads' tile-t loads in
        asm volatile("" ::: "memory");
#pragma unroll
        for (int kk = 0; kk < 2; ++kk) {
            const int ccA = (((kk << 2) + lg) ^ xA) << 3;   // swizzled col (f16)
            const int ccB = (((kk << 2) + lg) ^ xB) << 3;
            v8h av[8], bv[4];
#pragma unroll
            for (int m = 0; m < 8; ++m)
                av[m] = *(const v8h*)(&sA[cb][(rA << 6) + (m << 10) + ccA]);
#pragma unroll
            for (int n = 0; n < 4; ++n)
                bv[n] = *(const v8h*)(&sB[cb][(rB << 6) + (n << 10) + ccB]);
            asm volatile("s_waitcnt lgkmcnt(0)" ::: "memory");
            __builtin_amdgcn_sched_barrier(0);
            __builtin_amdgcn_s_setprio(1);
#pragma unroll
            for (int m = 0; m < 8; ++m)
#pragma unroll
                for (int n = 0; n < 4; ++n)
                    acc[m][n] = MFMA_F16(av[m], bv[n], acc[m][n]);
            __builtin_amdgcn_s_setprio(0);
        }
        __builtin_amdgcn_s_barrier();            // tile-t reads done before any
        asm volatile("" ::: "memory");           // t+2 load lands in buf[cb]
    }
#undef STAGE

#pragma unroll
    for (int n = 0; n < 4; ++n) {
        const int col = n0 + (wn << 6) + (n << 4) + l15;
        const float bvv = bias[col];
#pragma unroll
        for (int m = 0; m < 8; ++m) {
#pragma unroll
            for (int r = 0; r < 4; ++r) {
                const int row = m0 + (wm << 7) + (m << 4) + (lg << 2) + r;
                float v = acc[m][n][r] + bvv;
                if (MODE == 0) v += pos[((size_t)(row & 255) << 12) + col];
                if (MODE == 2)
                    Cf[((size_t)row << 12) + col] = v;
                else
                    Ch[((size_t)row << 12) + col] = (f16)v;
            }
        }
    }
}

// ---------------- f16 scores + softmax -> P fp32 (out1) + P f16 (PV) --------
// grid = 128 (b,h) * 4 q-slabs of 64 rows; block computes 64x256 scores.
__global__ __launch_bounds__(256)
void attn_scores(const f16* __restrict__ q, const f16* __restrict__ k,
                 float* __restrict__ Pf, f16* __restrict__ Pb) {
    const int blk = blockIdx.x;
    const int bh = blk >> 2, it = blk & 3;
    const int b = bh >> 3, h = bh & 7;
    const size_t qoff = ((size_t)(b * 256 + it * 64) << 12) + (h << 9);
    const size_t koff = ((size_t)(b * 256) << 12) + (h << 9);
    __shared__ __align__(16) u16 Qs[64 * 64];
    __shared__ __align__(16) u16 Ks[256 * 64];
    __shared__ float red[4][64];

    const int t = threadIdx.x;
    const int lane = t & 63, w = t >> 6;
    const int l15 = lane & 15, lg = lane >> 4;

    vf32x4 acc[4][4] = {};

    for (int k0 = 0; k0 < 512; k0 += 64) {
#pragma unroll
        for (int i = 0; i < 2; ++i) {               // Q slab: 64x64
            const int c = t + (i << 8);
            const int row = c >> 3, c8 = (c & 7) << 3;
            gld16(q + qoff + ((size_t)row << 12) + k0 + c8, Qs + c * 8);
        }
#pragma unroll
        for (int i = 0; i < 8; ++i) {               // K: 256x64
            const int c = t + (i << 8);
            const int row = c >> 3, c8 = (c & 7) << 3;
            gld16(k + koff + ((size_t)row << 12) + k0 + c8, Ks + c * 8);
        }
        __syncthreads();
#pragma unroll
        for (int kk = 0; kk < 2; ++kk) {
            v8h af[4], bf[4];
#pragma unroll
            for (int m = 0; m < 4; ++m)
                af[m] = *(const v8h*)(Qs + (m * 16 + l15) * 64 + kk * 32 + lg * 8);
#pragma unroll
            for (int n = 0; n < 4; ++n)
                bf[n] = *(const v8h*)(Ks + (w * 64 + n * 16 + l15) * 64 + kk * 32 + lg * 8);
#pragma unroll
            for (int m = 0; m < 4; ++m)
#pragma unroll
                for (int n = 0; n < 4; ++n)
                    acc[m][n] = MFMA_F16(af[m], bf[n], acc[m][n]);
        }
        __syncthreads();
    }

#pragma unroll
    for (int m = 0; m < 4; ++m)
#pragma unroll
        for (int n = 0; n < 4; ++n) acc[m][n] *= 0.125f;

    // row max: lane-local over n, shfl over 16-lane col group, LDS over waves
    float gm[4][4];
#pragma unroll
    for (int m = 0; m < 4; ++m)
#pragma unroll
        for (int r = 0; r < 4; ++r) {
            float v = fmaxf(fmaxf(acc[m][0][r], acc[m][1][r]),
                            fmaxf(acc[m][2][r], acc[m][3][r]));
#pragma unroll
            for (int off = 1; off < 16; off <<= 1) v = fmaxf(v, __shfl_xor(v, off));
            gm[m][r] = v;
        }
    if (l15 == 0) {
#pragma unroll
        for (int m = 0; m < 4; ++m)
#pragma unroll
            for (int r = 0; r < 4; ++r) red[w][m * 16 + lg * 4 + r] = gm[m][r];
    }
    __syncthreads();
#pragma unroll
    for (int m = 0; m < 4; ++m)
#pragma unroll
        for (int r = 0; r < 4; ++r) {
            const int row = m * 16 + lg * 4 + r;
            gm[m][r] = fmaxf(fmaxf(red[0][row], red[1][row]),
                             fmaxf(red[2][row], red[3][row]));
        }
    __syncthreads();   // protect red reuse

    // exp + row sum
    float gs[4][4];
#pragma unroll
    for (int m = 0; m < 4; ++m)
#pragma unroll
        for (int r = 0; r < 4; ++r) {
            float s = 0.f;
#pragma unroll
            for (int n = 0; n < 4; ++n) {
                const float e = __expf(acc[m][n][r] - gm[m][r]);
                acc[m][n][r] = e;
                s += e;
            }
#pragma unroll
            for (int off = 1; off < 16; off <<= 1) s += __shfl_xor(s, off);
            gs[m][r] = s;
        }
    if (l15 == 0) {
#pragma unroll
        for (int m = 0; m < 4; ++m)
#pragma unroll
            for (int r = 0; r < 4; ++r) red[w][m * 16 + lg * 4 + r] = gs[m][r];
    }
    __syncthreads();

    const size_t pbase = ((size_t)bh * 256 + it * 64) * 256;
#pragma unroll
    for (int m = 0; m < 4; ++m)
#pragma unroll
        for (int r = 0; r < 4; ++r) {
            const int row = m * 16 + lg * 4 + r;
            const float inv = 1.0f / (red[0][row] + red[1][row] +
                                      red[2][row] + red[3][row]);
#pragma unroll
            for (int n = 0; n < 4; ++n) {
                const int col = w * 64 + n * 16 + l15;
                const float p = acc[m][n][r] * inv;
                Pf[pbase + (size_t)row * 256 + col] = p;
                Pb[pbase + (size_t)row * 256 + col] = (f16)p;
            }
        }
}

// ---------------- PV: ao[b,n,h*512+j] = sum_m P[b,h,n,m] * v[b,m,h*512+j] ---
// grid = 128 bh * 2 m-tiles * 4 n-tiles; 128x128 tile; V staged transposed.
__global__ __launch_bounds__(256)
void attn_pv(const f16* __restrict__ P, const f16* __restrict__ V,
             f16* __restrict__ O) {
    __shared__ __align__(16) u16 Ps[128 * 64];
    __shared__ __align__(16) u16 Vt[128 * 72];   // [j][m], padded stride 72
    const int t = threadIdx.x;
    const int lane = t & 63, w = t >> 6;
    const int wr = (w >> 1) << 6, wc = (w & 1) << 6;
    const int l15 = lane & 15, lg = lane >> 4;
    const int blk = blockIdx.x;
    const int bh = blk >> 3, mt = (blk >> 2) & 1, nt = blk & 3;
    const int b = bh >> 3, h = bh & 7;
    const f16* Pbp = P + ((size_t)bh << 16) + ((size_t)mt << 15);
    const u16* Vb = (const u16*)V + ((size_t)(b * 256) << 12) + (h << 9) + (nt << 7);

    vf32x4 acc[4][4] = {};

    for (int k0 = 0; k0 < 256; k0 += 64) {
#pragma unroll
        for (int i = 0; i < 4; ++i) {               // P tile 128x64, linear
            const int c = t + (i << 8);
            const int row = c >> 3, c8 = (c & 7) << 3;
            gld16(Pbp + (size_t)row * 256 + k0 + c8, Ps + c * 8);
        }
#pragma unroll
        for (int pp = 0; pp < 4; ++pp) {            // V tile 64x128, transposed
            const int kr = pp * 16 + (t >> 4);
            const int c8 = (t & 15) << 3;
            vu16x8 vv = *(const vu16x8*)(Vb + ((size_t)(k0 + kr) << 12) + c8);
#pragma unroll
            for (int c = 0; c < 8; ++c) Vt[(c8 + c) * 72 + kr] = (u16)vv[c];
        }
        __syncthreads();
#pragma unroll
        for (int kk = 0; kk < 2; ++kk) {
            v8h af[4], bf[4];
#pragma unroll
            for (int m = 0; m < 4; ++m)
                af[m] = *(const v8h*)(Ps + (wr + m * 16 + l15) * 64 + kk * 32 + lg * 8);
#pragma unroll
            for (int n = 0; n < 4; ++n)
                bf[n] = *(const v8h*)(Vt + (wc + n * 16 + l15) * 72 + kk * 32 + lg * 8);
#pragma unroll
            for (int m = 0; m < 4; ++m)
#pragma unroll
                for (int n = 0; n < 4; ++n)
                    acc[m][n] = MFMA_F16(af[m], bf[n], acc[m][n]);
        }
        __syncthreads();
    }

#pragma unroll
    for (int m = 0; m < 4; ++m)
#pragma unroll
        for (int n = 0; n < 4; ++n) {
            const int col = (h << 9) + (nt << 7) + wc + n * 16 + l15;
#pragma unroll
            for (int r = 0; r < 4; ++r) {
                const int row = b * 256 + mt * 128 + wr + m * 16 + lg * 4 + r;
                O[((size_t)row << 12) + col] = (f16)acc[m][n][r];
            }
        }
}

// ---------------------------------------------------------------------------
extern "C" void kernel_launch(void* const* d_in, const int* in_sizes, int n_in,
                              void* d_out, int out_size, void* d_ws, size_t ws_size,
                              hipStream_t stream) {
    const float* x   = (const float*)d_in[0];
    const float* pos = (const float*)d_in[1];
    const float* wE  = (const float*)d_in[2];
    const float* bE  = (const float*)d_in[3];
    const float* wQ  = (const float*)d_in[4];
    const float* bq  = (const float*)d_in[5];
    const float* wK  = (const float*)d_in[6];
    const float* bk  = (const float*)d_in[7];
    const float* wV  = (const float*)d_in[8];
    const float* bv  = (const float*)d_in[9];
    const float* wO  = (const float*)d_in[10];
    const float* bo  = (const float*)d_in[11];

    float* out  = (float*)d_out;                    // output 0: 16,777,216 fp32
    float* Pout = out + (size_t)16777216;           // output 1:  8,388,608 fp32

    // ws layout (MiB offsets), peak 208 MiB
    char* W = (char*)d_ws;
    const size_t MB = 1024 * 1024;
    f16* xf    = (f16*)(W + 0 * MB);     // x f16; later ao (x dead post-embed)
    f16* wslab = (f16*)(W + 32 * MB);    // current weight f16
    f16* xe    = (f16*)(W + 64 * MB);    // embedded activations f16
    f16* qs    = (f16*)(W + 96 * MB);    // Q f16
    f16* ks    = (f16*)(W + 128 * MB);   // K f16
    f16* vs    = (f16*)(W + 160 * MB);   // V f16
    f16* Pb    = (f16*)(W + 192 * MB);   // P f16 (16 MiB)
    f16* ao    = xf;                     // PV result over x (dead)

    const int CVG = 16384;   // 16.7M elems / (256 thr * 4/thread)

    tof16<<<CVG, 256, 0, stream>>>(x, xf);
    tof16<<<CVG, 256, 0, stream>>>(wE, wslab);
    gemm8_nt<0><<<256, 512, 0, stream>>>(xf, wslab, bE, pos, xe, nullptr);

    tof16<<<CVG, 256, 0, stream>>>(wQ, wslab);
    gemm8_nt<1><<<256, 512, 0, stream>>>(xe, wslab, bq, nullptr, qs, nullptr);

    tof16<<<CVG, 256, 0, stream>>>(wK, wslab);
    gemm8_nt<1><<<256, 512, 0, stream>>>(xe, wslab, bk, nullptr, ks, nullptr);

    tof16<<<CVG, 256, 0, stream>>>(wV, wslab);
    gemm8_nt<1><<<256, 512, 0, stream>>>(xe, wslab, bv, nullptr, vs, nullptr);

    attn_scores<<<512, 256, 0, stream>>>(qs, ks, Pout, Pb);
    attn_pv<<<1024, 256, 0, stream>>>(Pb, vs, ao);

    tof16<<<CVG, 256, 0, stream>>>(wO, wslab);
    gemm8_nt<2><<<256, 512, 0, stream>>>(ao, wslab, bo, nullptr, nullptr, out);
}